// Round 2
// baseline (178.520 us; speedup 1.0000x reference)
//
#include <hip/hip_runtime.h>
#include <stdint.h>

typedef unsigned short u16;
typedef __bf16 bf16x8 __attribute__((ext_vector_type(8)));
typedef float f32x4 __attribute__((ext_vector_type(4)));

// E=8, D=512, H=256, T=64, B=16384
#define XV_N 8388608   // 16384*512
#define WE_N 1048576   // 8*256*512
#define WT_N 16384     // 64*256

__device__ __forceinline__ void glds16(const void* g, void* l) {
  __builtin_amdgcn_global_load_lds(
      (const __attribute__((address_space(1))) unsigned int*)g,
      (__attribute__((address_space(3))) unsigned int*)l, 16, 0, 0);
}

__device__ __forceinline__ u16 f2bf(float f) {
  unsigned int u = __builtin_bit_cast(unsigned int, f);
  u += 0x7fffu + ((u >> 16) & 1u);  // RNE (finite inputs)
  return (u16)(u >> 16);
}

__device__ __forceinline__ float bf2f(u16 u) {
  return __builtin_bit_cast(float, ((unsigned int)u) << 16);
}

// ---------------- convert: f32 -> bf16 for [xv | We | Wt], pure streaming ----------------
__global__ __launch_bounds__(256) void convert_kernel(
    const float* __restrict__ xv, const float* __restrict__ We,
    const float* __restrict__ Wt, u16* __restrict__ dst) {
  int idx = (blockIdx.x * 256 + threadIdx.x) * 8;
  const float* src;
  if (idx < XV_N) src = xv + idx;
  else if (idx < XV_N + WE_N) src = We + (idx - XV_N);
  else src = Wt + (idx - XV_N - WE_N);
  float4 a = *(const float4*)src;
  float4 b = *(const float4*)(src + 4);
  uint4 o;
  o.x = (unsigned)f2bf(a.x) | ((unsigned)f2bf(a.y) << 16);
  o.y = (unsigned)f2bf(a.z) | ((unsigned)f2bf(a.w) << 16);
  o.z = (unsigned)f2bf(b.x) | ((unsigned)f2bf(b.y) << 16);
  o.w = (unsigned)f2bf(b.z) | ((unsigned)f2bf(b.w) << 16);
  *(uint4*)(dst + idx) = o;
}

// ---------------- gate: softmax(xv @ Wg^T + bg) ----------------
// 8 rows per wave, 8 lanes per row (ksub = k-slice of 64), 3-step shuffle reduce.
__global__ __launch_bounds__(256) void gate_kernel(
    const u16* __restrict__ xv_bf, const float* __restrict__ Wg,
    const float* __restrict__ bg, float* __restrict__ gate) {
  const int tid = threadIdx.x, wid = tid >> 6, lane = tid & 63;
  const int rsub = lane >> 3, ksub = lane & 7;
  const int row = blockIdx.x * 32 + wid * 8 + rsub;
  const u16* xr = xv_bf + row * 512 + ksub * 64;
  float s[8] = {0.f, 0.f, 0.f, 0.f, 0.f, 0.f, 0.f, 0.f};
#pragma unroll
  for (int j = 0; j < 8; j++) {
    uint4 xp = *(const uint4*)(xr + j * 8);
    float x[8];
    x[0] = bf2f((u16)xp.x); x[1] = bf2f((u16)(xp.x >> 16));
    x[2] = bf2f((u16)xp.y); x[3] = bf2f((u16)(xp.y >> 16));
    x[4] = bf2f((u16)xp.z); x[5] = bf2f((u16)(xp.z >> 16));
    x[6] = bf2f((u16)xp.w); x[7] = bf2f((u16)(xp.w >> 16));
#pragma unroll
    for (int e = 0; e < 8; e++) {
      const float* wg = Wg + e * 512 + ksub * 64 + j * 8;
      float4 w0 = *(const float4*)wg;
      float4 w1 = *(const float4*)(wg + 4);
      s[e] += x[0] * w0.x + x[1] * w0.y + x[2] * w0.z + x[3] * w0.w +
              x[4] * w1.x + x[5] * w1.y + x[6] * w1.z + x[7] * w1.w;
    }
  }
#pragma unroll
  for (int e = 0; e < 8; e++) {
    s[e] += __shfl_xor(s[e], 1);
    s[e] += __shfl_xor(s[e], 2);
    s[e] += __shfl_xor(s[e], 4);
    s[e] += bg[e];
  }
  float mx = s[0];
#pragma unroll
  for (int e = 1; e < 8; e++) mx = fmaxf(mx, s[e]);
  float p[8], sum = 0.f;
#pragma unroll
  for (int e = 0; e < 8; e++) { p[e] = __expf(s[e] - mx); sum += p[e]; }
  float inv = 1.f / sum;
  if (ksub == 0) {
    float4 g0 = {p[0] * inv, p[1] * inv, p[2] * inv, p[3] * inv};
    float4 g1 = {p[4] * inv, p[5] * inv, p[6] * inv, p[7] * inv};
    *(float4*)(gate + row * 8) = g0;
    *(float4*)(gate + row * 8 + 4) = g1;
  }
}

// ---------------- main fused kernel ----------------
// grid 512: mb = bx&127 (128-row tile; same-mb -> same XCD), sub = bx>>7:
// ep = sub>>1 (experts eg0..eg0+3), hb = sub&1 (h-half of 128).
// Block: 512 threads = 8 waves (wm=wid>>2: 64-row half; wn=wid&3: 32-col slice).
// kc-outer (K=512 in 8 chunks of 64), expert-inner; A frags register-resident
// across all 4 experts. LDS 48 KB: A 16 KB + B(2 experts at a time) 32 KB.
__global__ __launch_bounds__(512, 2) void moe_main(
    const u16* __restrict__ xv_bf, const u16* __restrict__ We_bf,
    const float* __restrict__ be, const float* __restrict__ gate,
    const u16* __restrict__ Wt_bf, u16* __restrict__ part) {
  __shared__ u16 lds[24576];  // 48 KB

  const int bx = blockIdx.x;
  const int mb = bx & 127, sub = bx >> 7;
  const int ep = sub >> 1, hb = sub & 1;
  const int m0 = mb << 7, h0 = hb << 7, eg0 = ep << 2;
  const int tid = threadIdx.x, lane = tid & 63, wid = tid >> 6;
  const int wm = wid >> 2, wn = wid & 3;
  const int l15 = lane & 15, l4 = lane >> 4;

  f32x4 acc[4][4][2];
#pragma unroll
  for (int e = 0; e < 4; e++)
#pragma unroll
    for (int mt = 0; mt < 4; mt++)
#pragma unroll
      for (int nt = 0; nt < 2; nt++) acc[e][mt][nt] = {0.f, 0.f, 0.f, 0.f};

  for (int kc = 0; kc < 8; kc++) {
    const int kofs = kc << 6;
    __syncthreads();
    // stage A: 128 rows x 64 k, xor-swizzled 16B granules (slot s holds g=s^(row&7))
#pragma unroll
    for (int r = 0; r < 2; r++) {
      int gi = r * 512 + tid;
      int row = gi >> 3, s = gi & 7, g = s ^ (row & 7);
      glds16(xv_bf + ((m0 + row) << 9) + kofs + (g << 3), &lds[gi << 3]);
    }
    // stage B experts eg0+0, eg0+1
#pragma unroll
    for (int r = 0; r < 4; r++) {
      int gi = r * 512 + tid;
      int el = gi >> 10, rem = gi & 1023, n = rem >> 3, s = rem & 7, g = s ^ (n & 7);
      glds16(We_bf + ((eg0 + el) << 17) + ((h0 + n) << 9) + kofs + (g << 3),
             &lds[8192 + (gi << 3)]);
    }
    __syncthreads();
    // A fragments -> registers (reused across all 4 experts)
    bf16x8 af[4][2];
#pragma unroll
    for (int mt = 0; mt < 4; mt++)
#pragma unroll
      for (int ks = 0; ks < 2; ks++) {
        int row = wm * 64 + mt * 16 + l15;
        int gg = ks * 4 + l4;
        int slot = gg ^ (row & 7);
        af[mt][ks] = *(const bf16x8*)&lds[(row << 6) + (slot << 3)];
      }
    // compute experts 0,1
#pragma unroll
    for (int el = 0; el < 2; el++)
#pragma unroll
      for (int ks = 0; ks < 2; ks++) {
        bf16x8 bf[2];
#pragma unroll
        for (int nt = 0; nt < 2; nt++) {
          int n = wn * 32 + nt * 16 + l15;
          int gg = ks * 4 + l4;
          int slot = gg ^ (n & 7);
          bf[nt] = *(const bf16x8*)&lds[8192 + (el << 13) + (n << 6) + (slot << 3)];
        }
#pragma unroll
        for (int mt = 0; mt < 4; mt++)
#pragma unroll
          for (int nt = 0; nt < 2; nt++)
            acc[el][mt][nt] = __builtin_amdgcn_mfma_f32_16x16x32_bf16(
                af[mt][ks], bf[nt], acc[el][mt][nt], 0, 0, 0);
      }
    __syncthreads();
    // stage B experts eg0+2, eg0+3 (overwrite B region; A untouched)
#pragma unroll
    for (int r = 0; r < 4; r++) {
      int gi = r * 512 + tid;
      int el = gi >> 10, rem = gi & 1023, n = rem >> 3, s = rem & 7, g = s ^ (n & 7);
      glds16(We_bf + ((eg0 + 2 + el) << 17) + ((h0 + n) << 9) + kofs + (g << 3),
             &lds[8192 + (gi << 3)]);
    }
    __syncthreads();
    // compute experts 2,3 (A frags still in registers)
#pragma unroll
    for (int el = 0; el < 2; el++)
#pragma unroll
      for (int ks = 0; ks < 2; ks++) {
        bf16x8 bf[2];
#pragma unroll
        for (int nt = 0; nt < 2; nt++) {
          int n = wn * 32 + nt * 16 + l15;
          int gg = ks * 4 + l4;
          int slot = gg ^ (n & 7);
          bf[nt] = *(const bf16x8*)&lds[8192 + (el << 13) + (n << 6) + (slot << 3)];
        }
#pragma unroll
        for (int mt = 0; mt < 4; mt++)
#pragma unroll
          for (int nt = 0; nt < 2; nt++)
            acc[2 + el][mt][nt] = __builtin_amdgcn_mfma_f32_16x16x32_bf16(
                af[mt][ks], bf[nt], acc[2 + el][mt][nt], 0, 0, 0);
      }
  }

  // ---- epilogue: comb = sum_e gate[row,eg0+e] * relu(acc_e + be[e,col])
  float bev[4][2];
#pragma unroll
  for (int e = 0; e < 4; e++)
#pragma unroll
    for (int nt = 0; nt < 2; nt++)
      bev[e][nt] = be[(eg0 + e) * 256 + h0 + wn * 32 + nt * 16 + l15];

  f32x4 comb[4][2];
#pragma unroll
  for (int mt = 0; mt < 4; mt++) {
#pragma unroll
    for (int i = 0; i < 4; i++) {
      int row = m0 + wm * 64 + mt * 16 + l4 * 4 + i;
      float4 gv4 = *(const float4*)&gate[(row << 3) + eg0];
      const float* gv = &gv4.x;
#pragma unroll
      for (int nt = 0; nt < 2; nt++) {
        float c = 0.f;
#pragma unroll
        for (int e = 0; e < 4; e++)
          c += gv[e] * fmaxf(acc[e][mt][nt][i] + bev[e][nt], 0.f);
        comb[mt][nt][i] = c;
      }
    }
  }

  // ---- tower partial over this block's 128 h-cols -> part[sub][128 rows][64 t]
  __syncthreads();
#pragma unroll
  for (int mt = 0; mt < 4; mt++)
#pragma unroll
    for (int i = 0; i < 4; i++) {
      int row = wm * 64 + mt * 16 + l4 * 4 + i;
#pragma unroll
      for (int nt = 0; nt < 2; nt++) {
        int col = wn * 32 + nt * 16 + l15;
        lds[row * 136 + col] = f2bf(comb[mt][nt][i]);
      }
    }
  __syncthreads();
  f32x4 tacc[4];
#pragma unroll
  for (int nt = 0; nt < 4; nt++) tacc[nt] = {0.f, 0.f, 0.f, 0.f};
  const int trow = wid * 16 + l15;
#pragma unroll
  for (int ks = 0; ks < 4; ks++) {
    bf16x8 aT = *(const bf16x8*)&lds[trow * 136 + ks * 32 + l4 * 8];
#pragma unroll
    for (int nt = 0; nt < 4; nt++) {
      bf16x8 bT = *(const bf16x8*)&Wt_bf[(nt * 16 + l15) * 256 + h0 + ks * 32 + l4 * 8];
      tacc[nt] = __builtin_amdgcn_mfma_f32_16x16x32_bf16(aT, bT, tacc[nt], 0, 0, 0);
    }
  }
  u16* pout = part + sub * 1048576;
#pragma unroll
  for (int nt = 0; nt < 4; nt++)
#pragma unroll
    for (int i = 0; i < 4; i++) {
      int grow = m0 + wid * 16 + l4 * 4 + i;
      pout[grow * 64 + nt * 16 + l15] = f2bf(tacc[nt][i]);
    }
}

// ---------------- finish: sigmoid(sum of 4 bf16 partials + bt) ----------------
__global__ __launch_bounds__(256) void finish_kernel(
    const u16* __restrict__ part, const float* __restrict__ bt,
    float* __restrict__ out) {
  const int base = (blockIdx.x * 256 + threadIdx.x) * 8;
  float a[8] = {0.f, 0.f, 0.f, 0.f, 0.f, 0.f, 0.f, 0.f};
#pragma unroll
  for (int s = 0; s < 4; s++) {
    uint4 p = *(const uint4*)(part + s * 1048576 + base);
    a[0] += bf2f((u16)p.x); a[1] += bf2f((u16)(p.x >> 16));
    a[2] += bf2f((u16)p.y); a[3] += bf2f((u16)(p.y >> 16));
    a[4] += bf2f((u16)p.z); a[5] += bf2f((u16)(p.z >> 16));
    a[6] += bf2f((u16)p.w); a[7] += bf2f((u16)(p.w >> 16));
  }
  const int t0 = base & 63;
  float4 b0 = *(const float4*)(bt + t0);
  float4 b1 = *(const float4*)(bt + t0 + 4);
  const float* bb = &b0.x;
  float r[8];
#pragma unroll
  for (int j = 0; j < 8; j++) {
    float bj = (j < 4) ? bb[j] : (&b1.x)[j - 4];
    r[j] = 1.f / (1.f + __expf(-(a[j] + bj)));
  }
  float4 o0 = {r[0], r[1], r[2], r[3]};
  float4 o1 = {r[4], r[5], r[6], r[7]};
  *(float4*)(out + base) = o0;
  *(float4*)(out + base + 4) = o1;
}

extern "C" void kernel_launch(void* const* d_in, const int* in_sizes, int n_in,
                              void* d_out, int out_size, void* d_ws, size_t ws_size,
                              hipStream_t stream) {
  const float* xv = (const float*)d_in[0];
  const float* We = (const float*)d_in[1];
  const float* be = (const float*)d_in[2];
  const float* Wg = (const float*)d_in[3];
  const float* bg = (const float*)d_in[4];
  const float* Wt = (const float*)d_in[5];
  const float* bt = (const float*)d_in[6];

  char* ws = (char*)d_ws;
  u16* cvt = (u16*)ws;                        // bf16 [xv | We | Wt]: 18,907,136 B
  u16* xv_bf = cvt;
  u16* We_bf = cvt + XV_N;
  u16* Wt_bf = cvt + XV_N + WE_N;
  float* gate = (float*)(ws + 18907136);      // 512 KB
  u16* part = (u16*)(ws + 19431424);          // 4 x 16384 x 64 bf16 = 8 MB
  // total ws use: 27,820,032 B (same footprint as round 0 -> known safe)

  convert_kernel<<<4616, 256, 0, stream>>>(xv, We, Wt, cvt);
  gate_kernel<<<512, 256, 0, stream>>>(xv_bf, Wg, bg, gate);
  moe_main<<<512, 512, 0, stream>>>(xv_bf, We_bf, be, gate, Wt_bf, part);
  finish_kernel<<<512, 256, 0, stream>>>(part, bt, (float*)d_out);
}

// Round 3
// 159.261 us; speedup vs baseline: 1.1209x; 1.1209x over previous
//
#include <hip/hip_runtime.h>
#include <stdint.h>

typedef unsigned short u16;
typedef __bf16 bf16x8 __attribute__((ext_vector_type(8)));
typedef float f32x4 __attribute__((ext_vector_type(4)));
typedef float f32x16 __attribute__((ext_vector_type(16)));

// E=8, D=512, H=256, T=64, B=16384
#define XV_N 8388608   // 16384*512
#define WE_N 1048576   // 8*256*512

__device__ __forceinline__ void glds16(const void* g, void* l) {
  __builtin_amdgcn_global_load_lds(
      (const __attribute__((address_space(1))) unsigned int*)g,
      (__attribute__((address_space(3))) unsigned int*)l, 16, 0, 0);
}

__device__ __forceinline__ u16 f2bf(float f) {
  unsigned int u = __builtin_bit_cast(unsigned int, f);
  u += 0x7fffu + ((u >> 16) & 1u);  // RNE (finite inputs)
  return (u16)(u >> 16);
}

__device__ __forceinline__ float bf2f(u16 u) {
  return __builtin_bit_cast(float, ((unsigned int)u) << 16);
}

// ---------------- prep: bf16 conversion + gate softmax (round-0 structure) ----------------
// blocks 0..4095: 4 rows each (one wave per row): convert xv row + gate softmax
// blocks 4096..4615: convert We (512 blocks) then Wt (8 blocks), 2048 elems each
__global__ __launch_bounds__(256) void prep_kernel(
    const float* __restrict__ xv, const float* __restrict__ We,
    const float* __restrict__ Wg, const float* __restrict__ bg,
    const float* __restrict__ Wt,
    u16* __restrict__ xv_bf, u16* __restrict__ We_bf,
    u16* __restrict__ Wt_bf, float* __restrict__ gate) {
  const int bx = blockIdx.x;
  if (bx < 4096) {
    const int wid = threadIdx.x >> 6, lane = threadIdx.x & 63;
    const int row = bx * 4 + wid;
    const float* xr = xv + (row << 9) + lane * 8;
    float4 x0 = *(const float4*)xr;
    float4 x1 = *(const float4*)(xr + 4);
    uint4 o;
    o.x = (unsigned)f2bf(x0.x) | ((unsigned)f2bf(x0.y) << 16);
    o.y = (unsigned)f2bf(x0.z) | ((unsigned)f2bf(x0.w) << 16);
    o.z = (unsigned)f2bf(x1.x) | ((unsigned)f2bf(x1.y) << 16);
    o.w = (unsigned)f2bf(x1.z) | ((unsigned)f2bf(x1.w) << 16);
    *(uint4*)(xv_bf + (row << 9) + lane * 8) = o;
    // gate logits
    float s[8];
#pragma unroll
    for (int e = 0; e < 8; e++) {
      const float* wg = Wg + (e << 9) + lane * 8;
      float4 w0 = *(const float4*)wg;
      float4 w1 = *(const float4*)(wg + 4);
      s[e] = x0.x * w0.x + x0.y * w0.y + x0.z * w0.z + x0.w * w0.w +
             x1.x * w1.x + x1.y * w1.y + x1.z * w1.z + x1.w * w1.w;
    }
#pragma unroll
    for (int e = 0; e < 8; e++) {
#pragma unroll
      for (int off = 32; off > 0; off >>= 1) s[e] += __shfl_xor(s[e], off);
      s[e] += bg[e];
    }
    float mx = s[0];
#pragma unroll
    for (int e = 1; e < 8; e++) mx = fmaxf(mx, s[e]);
    float p[8], sum = 0.f;
#pragma unroll
    for (int e = 0; e < 8; e++) { p[e] = __expf(s[e] - mx); sum += p[e]; }
    float inv = 1.f / sum;
    if (lane == 0) {
      float4 g0 = {p[0] * inv, p[1] * inv, p[2] * inv, p[3] * inv};
      float4 g1 = {p[4] * inv, p[5] * inv, p[6] * inv, p[7] * inv};
      *(float4*)(gate + row * 8) = g0;
      *(float4*)(gate + row * 8 + 4) = g1;
    }
  } else {
    const int base = (bx - 4096) * 2048 + threadIdx.x * 8;
    const float* src;
    u16* dst;
    if (base < WE_N) { src = We + base; dst = We_bf + base; }
    else { src = Wt + (base - WE_N); dst = Wt_bf + (base - WE_N); }
    float4 a = *(const float4*)src;
    float4 b = *(const float4*)(src + 4);
    uint4 o;
    o.x = (unsigned)f2bf(a.x) | ((unsigned)f2bf(a.y) << 16);
    o.y = (unsigned)f2bf(a.z) | ((unsigned)f2bf(a.w) << 16);
    o.z = (unsigned)f2bf(b.x) | ((unsigned)f2bf(b.y) << 16);
    o.w = (unsigned)f2bf(b.z) | ((unsigned)f2bf(b.w) << 16);
    *(uint4*)dst = o;
  }
}

// ---------------- main fused kernel (32x32x16 MFMA) ----------------
// grid 1024: e = bx&7 (-> XCD = expert, L2-resident weights), mb = bx>>3.
// Block: 256 thr = 4 waves (wm=wid>>1: 64-row half; wn=wid&1: 128-col half).
// Tile: 128 rows x 256 h x 1 expert; kc=64, 8 iters, 2 barriers/kc.
// Wave: 64x128 as (mt=2)x(nt=4) of 32x32 -> acc 2x4x16 = 128 VGPR.
// Per wave per kc: 8 A + 16 B ds_read_b128 for 32 MFMA (0.047 B/MAC).
// Epilogue: fold gate*relu(acc+be) -> comb bf16 in LDS (2 halves) -> tower
// partial (16x16x32) -> part[e][16384][64] bf16.
__global__ __launch_bounds__(256, 2) void moe_main(
    const u16* __restrict__ xv_bf, const u16* __restrict__ We_bf,
    const float* __restrict__ be, const float* __restrict__ gate,
    const u16* __restrict__ Wt_bf, u16* __restrict__ part) {
  __shared__ u16 lds[24576];  // 48 KB: A [128][64] + B [256][64] (swizzled)

  const int bx = blockIdx.x;
  const int e = bx & 7, mb = bx >> 3;
  const int m0 = mb << 7;
  const int tid = threadIdx.x, lane = tid & 63, wid = tid >> 6;
  const int wm = wid >> 1, wn = wid & 1;
  const int l31 = lane & 31, lhi = lane >> 5;
  const int l15 = lane & 15, l4 = lane >> 4;

  f32x16 acc[2][4];
#pragma unroll
  for (int mt = 0; mt < 2; mt++)
#pragma unroll
    for (int nt = 0; nt < 4; nt++)
#pragma unroll
      for (int r = 0; r < 16; r++) acc[mt][nt][r] = 0.f;

  const u16* Wb = We_bf + (e << 17);
  for (int kc = 0; kc < 8; kc++) {
    const int kofs = kc << 6;
    __syncthreads();
    // stage A: 128 rows x 64 k; slot s holds granule g = s^(row&7)
#pragma unroll
    for (int r = 0; r < 4; r++) {
      int gi = r * 256 + tid;
      int m = gi >> 3, s = gi & 7, g = s ^ (m & 7);
      glds16(xv_bf + ((m0 + m) << 9) + kofs + (g << 3), &lds[gi << 3]);
    }
    // stage B: 256 h-rows x 64 k
#pragma unroll
    for (int r = 0; r < 8; r++) {
      int gi = r * 256 + tid;
      int n = gi >> 3, s = gi & 7, g = s ^ (n & 7);
      glds16(Wb + (n << 9) + kofs + (g << 3), &lds[8192 + (gi << 3)]);
    }
    __syncthreads();
#pragma unroll
    for (int ks = 0; ks < 4; ks++) {
      const int gg = ks * 2 + lhi;
      bf16x8 af[2];
#pragma unroll
      for (int mt = 0; mt < 2; mt++) {
        int m = wm * 64 + mt * 32 + l31;
        int slot = gg ^ (m & 7);
        af[mt] = *(const bf16x8*)&lds[(m << 6) + (slot << 3)];
      }
      bf16x8 bfr[4];
#pragma unroll
      for (int nt = 0; nt < 4; nt++) {
        int n = wn * 128 + nt * 32 + l31;
        int slot = gg ^ (n & 7);
        bfr[nt] = *(const bf16x8*)&lds[8192 + (n << 6) + (slot << 3)];
      }
#pragma unroll
      for (int mt = 0; mt < 2; mt++)
#pragma unroll
        for (int nt = 0; nt < 4; nt++)
          acc[mt][nt] = __builtin_amdgcn_mfma_f32_32x32x16_bf16(
              af[mt], bfr[nt], acc[mt][nt], 0, 0, 0);
    }
  }

  // ---- epilogue: comb = gate[row,e] * relu(acc + be[e,col]) ----
  float bev[4];
#pragma unroll
  for (int nt = 0; nt < 4; nt++)
    bev[nt] = be[(e << 8) + wn * 128 + nt * 32 + l31];

  f32x4 tacc[2][4];
#pragma unroll
  for (int mt = 0; mt < 2; mt++)
#pragma unroll
    for (int nt = 0; nt < 4; nt++) tacc[mt][nt] = {0.f, 0.f, 0.f, 0.f};

  __syncthreads();  // all waves done reading A/B before comb overwrites LDS

  // two h-halves through LDS (comb [128 rows][136 cols] bf16 = 34 KB)
#pragma unroll
  for (int half = 0; half < 2; half++) {
    if (wn == half) {
#pragma unroll
      for (int mt = 0; mt < 2; mt++) {
#pragma unroll
        for (int r = 0; r < 16; r++) {
          int rowpat = (r & 3) + 8 * (r >> 2) + 4 * lhi;
          int row = wm * 64 + mt * 32 + rowpat;
          float g = gate[((m0 + row) << 3) + e];
#pragma unroll
          for (int nt = 0; nt < 4; nt++) {
            float c = g * fmaxf(acc[mt][nt][r] + bev[nt], 0.f);
            lds[row * 136 + nt * 32 + l31] = f2bf(c);
          }
        }
      }
    }
    __syncthreads();
    // tower partial: K-slice h in [half*128, half*128+128)
#pragma unroll
    for (int ks = 0; ks < 4; ks++) {
#pragma unroll
      for (int mtt = 0; mtt < 2; mtt++) {
        bf16x8 aT = *(const bf16x8*)&lds[(wid * 32 + mtt * 16 + l15) * 136 +
                                         ks * 32 + l4 * 8];
#pragma unroll
        for (int ntt = 0; ntt < 4; ntt++) {
          bf16x8 bT = *(const bf16x8*)&Wt_bf[(ntt * 16 + l15) * 256 +
                                             half * 128 + ks * 32 + l4 * 8];
          tacc[mtt][ntt] = __builtin_amdgcn_mfma_f32_16x16x32_bf16(
              aT, bT, tacc[mtt][ntt], 0, 0, 0);
        }
      }
    }
    __syncthreads();
  }

  u16* pout = part + (e << 20);  // e * 16384 * 64
#pragma unroll
  for (int mtt = 0; mtt < 2; mtt++)
#pragma unroll
    for (int ntt = 0; ntt < 4; ntt++)
#pragma unroll
      for (int i = 0; i < 4; i++) {
        int grow = m0 + wid * 32 + mtt * 16 + l4 * 4 + i;
        pout[grow * 64 + ntt * 16 + l15] = f2bf(tacc[mtt][ntt][i]);
      }
}

// ---------------- finish: sigmoid(sum of 8 bf16 partials + bt) ----------------
__global__ __launch_bounds__(256) void finish_kernel(
    const u16* __restrict__ part, const float* __restrict__ bt,
    float* __restrict__ out) {
  const int base = (blockIdx.x * 256 + threadIdx.x) * 8;
  float a[8] = {0.f, 0.f, 0.f, 0.f, 0.f, 0.f, 0.f, 0.f};
#pragma unroll
  for (int s = 0; s < 8; s++) {
    uint4 p = *(const uint4*)(part + s * 1048576 + base);
    a[0] += bf2f((u16)p.x); a[1] += bf2f((u16)(p.x >> 16));
    a[2] += bf2f((u16)p.y); a[3] += bf2f((u16)(p.y >> 16));
    a[4] += bf2f((u16)p.z); a[5] += bf2f((u16)(p.z >> 16));
    a[6] += bf2f((u16)p.w); a[7] += bf2f((u16)(p.w >> 16));
  }
  const int t0 = base & 63;
  float4 b0 = *(const float4*)(bt + t0);
  float4 b1 = *(const float4*)(bt + t0 + 4);
  float r[8];
#pragma unroll
  for (int j = 0; j < 8; j++) {
    float bj = (j < 4) ? (&b0.x)[j] : (&b1.x)[j - 4];
    r[j] = 1.f / (1.f + __expf(-(a[j] + bj)));
  }
  float4 o0 = {r[0], r[1], r[2], r[3]};
  float4 o1 = {r[4], r[5], r[6], r[7]};
  *(float4*)(out + base) = o0;
  *(float4*)(out + base + 4) = o1;
}

extern "C" void kernel_launch(void* const* d_in, const int* in_sizes, int n_in,
                              void* d_out, int out_size, void* d_ws, size_t ws_size,
                              hipStream_t stream) {
  const float* xv = (const float*)d_in[0];
  const float* We = (const float*)d_in[1];
  const float* be = (const float*)d_in[2];
  const float* Wg = (const float*)d_in[3];
  const float* bg = (const float*)d_in[4];
  const float* Wt = (const float*)d_in[5];
  const float* bt = (const float*)d_in[6];

  char* ws = (char*)d_ws;
  u16* xv_bf = (u16*)ws;                       // 16 MB
  u16* We_bf = (u16*)(ws + 16777216);          // 2 MB
  u16* Wt_bf = (u16*)(ws + 18874368);          // 32 KB
  float* gate = (float*)(ws + 18907136);       // 512 KB
  u16* part = (u16*)(ws + 19431424);           // 8 x 16384 x 64 bf16 = 16 MB
  // total ws use: 36,208,640 B

  prep_kernel<<<4616, 256, 0, stream>>>(xv, We, Wg, bg, Wt, xv_bf, We_bf, Wt_bf, gate);
  moe_main<<<1024, 256, 0, stream>>>(xv_bf, We_bf, be, gate, Wt_bf, part);
  finish_kernel<<<512, 256, 0, stream>>>(part, bt, (float*)d_out);
}